// Round 13
// baseline (244.869 us; speedup 1.0000x reference)
//
#include <hip/hip_runtime.h>
#include <hip/hip_bf16.h>
#include <math.h>

// Problem constants
#define BB 8
#define TT 704
#define DD 1024
#define RR 16
#define KK 4
#define HDH 64
#define BT (BB*TT)   // 5632

typedef unsigned short u16;
typedef __attribute__((ext_vector_type(4))) float f32x4;
typedef __attribute__((ext_vector_type(8))) short bf16x8;
typedef __attribute__((ext_vector_type(4))) unsigned short u16x4;
typedef __attribute__((ext_vector_type(8))) unsigned short u16x8;

__device__ __forceinline__ u16 f2bf(float f) {
    union { float f; unsigned int u; } cv; cv.f = f;
    unsigned int u = cv.u;
    unsigned int r = (u + 0x7fffu + ((u >> 16) & 1u)) >> 16;
    return (u16)r;
}

__device__ __forceinline__ float bf2f(u16 v) {
    union { unsigned int u; float f; } cv; cv.u = ((unsigned int)v) << 16;
    return cv.f;
}

// fast gelu: 0.5x(1+tanh(0.79788456(x+0.044715x^3))), tanh via one __expf
__device__ __forceinline__ float gelu_fast(float x) {
    const float y = 0.7978845608028654f * (x + 0.044715f * x * x * x);
    const float ay = fabsf(y);
    const float t = 1.f - 2.f / (__expf(2.f * ay) + 1.f);   // tanh(|y|)
    const float th = (y < 0.f) ? -t : t;
    return 0.5f * x * (1.f + th);
}

__device__ __forceinline__ void gl2lds(const u16* g, u16* l) {
    __builtin_amdgcn_global_load_lds(
        (const __attribute__((address_space(1))) void*)g,
        (__attribute__((address_space(3))) void*)l, 16, 0, 0);
}

template<int N> __device__ __forceinline__ void waitv() {
    if constexpr (N == 0) asm volatile("s_waitcnt vmcnt(0)" ::: "memory");
    else if constexpr (N == 2) asm volatile("s_waitcnt vmcnt(2)" ::: "memory");
    else if constexpr (N == 3) asm volatile("s_waitcnt vmcnt(3)" ::: "memory");
    else asm volatile("s_waitcnt vmcnt(4)" ::: "memory");
}

// XCD-chunked swizzle: physical d -> logical bid so that each XCD (d%8) gets
// a CONTIGUOUS chunk of logical block ids (L2 locality). Requires nwg%8==0.
__device__ __forceinline__ int xcd_swz(int d, int nwg) {
    return (d & 7) * (nwg >> 3) + (d >> 3);
}

// ---------------------------------------------------------- LayerNorm (LN2)
template<int OBF16, int IBF16>
__global__ __launch_bounds__(256)
void ln_kernel(const void* __restrict__ xv, const float* __restrict__ g,
               const float* __restrict__ be, void* __restrict__ yv)
{
    const int row = blockIdx.x;
    const int tid = threadIdx.x;
    __shared__ float sbuf[4];
    const size_t off = (size_t)row * DD + tid * 4;
    float4 v;
    if (IBF16) {
        u16x4 xb = *(const u16x4*)((const u16*)xv + off);
        v.x = bf2f(xb[0]); v.y = bf2f(xb[1]); v.z = bf2f(xb[2]); v.w = bf2f(xb[3]);
    } else {
        v = *(const float4*)((const float*)xv + off);
    }
    float s = v.x + v.y + v.z + v.w;
#pragma unroll
    for (int o = 32; o; o >>= 1) s += __shfl_xor(s, o);
    if ((tid & 63) == 0) sbuf[tid >> 6] = s;
    __syncthreads();
    float mean = (sbuf[0] + sbuf[1] + sbuf[2] + sbuf[3]) * (1.f / 1024.f);
    float dx = v.x - mean, dy = v.y - mean, dz = v.z - mean, dw = v.w - mean;
    float q = dx*dx + dy*dy + dz*dz + dw*dw;
    __syncthreads();
#pragma unroll
    for (int o = 32; o; o >>= 1) q += __shfl_xor(q, o);
    if ((tid & 63) == 0) sbuf[tid >> 6] = q;
    __syncthreads();
    float var = (sbuf[0] + sbuf[1] + sbuf[2] + sbuf[3]) * (1.f / 1024.f);
    float rstd = rsqrtf(var + 1e-5f);
    float4 gg = *(const float4*)(g + tid * 4);
    float4 bb4 = *(const float4*)(be + tid * 4);
    float o0 = dx * rstd * gg.x + bb4.x;
    float o1 = dy * rstd * gg.y + bb4.y;
    float o2 = dz * rstd * gg.z + bb4.z;
    float o3 = dw * rstd * gg.w + bb4.w;
    if (OBF16) {
        u16x4 o4 = {f2bf(o0), f2bf(o1), f2bf(o2), f2bf(o3)};
        *(u16x4*)((u16*)yv + off) = o4;
    } else {
        float4 o4 = {o0, o1, o2, o3};
        *(float4*)((float*)yv + off) = o4;
    }
}

// ------------------------------- LN1: writes fp32 (pool path) + bf16 (GEMMs)
__global__ __launch_bounds__(256)
void ln1_dual_kernel(const float* __restrict__ x, const float* __restrict__ g,
                     const float* __restrict__ be, float* __restrict__ y,
                     u16* __restrict__ yb)
{
    const int row = blockIdx.x;
    const int tid = threadIdx.x;
    __shared__ float sbuf[4];
    const size_t off = (size_t)row * DD + tid * 4;
    float4 v = *(const float4*)(x + off);
    float s = v.x + v.y + v.z + v.w;
#pragma unroll
    for (int o = 32; o; o >>= 1) s += __shfl_xor(s, o);
    if ((tid & 63) == 0) sbuf[tid >> 6] = s;
    __syncthreads();
    float mean = (sbuf[0] + sbuf[1] + sbuf[2] + sbuf[3]) * (1.f / 1024.f);
    float dx = v.x - mean, dy = v.y - mean, dz = v.z - mean, dw = v.w - mean;
    float q = dx*dx + dy*dy + dz*dz + dw*dw;
    __syncthreads();
#pragma unroll
    for (int o = 32; o; o >>= 1) q += __shfl_xor(q, o);
    if ((tid & 63) == 0) sbuf[tid >> 6] = q;
    __syncthreads();
    float var = (sbuf[0] + sbuf[1] + sbuf[2] + sbuf[3]) * (1.f / 1024.f);
    float rstd = rsqrtf(var + 1e-5f);
    float4 gg = *(const float4*)(g + tid * 4);
    float4 bb4 = *(const float4*)(be + tid * 4);
    float o0 = dx * rstd * gg.x + bb4.x;
    float o1 = dy * rstd * gg.y + bb4.y;
    float o2 = dz * rstd * gg.z + bb4.z;
    float o3 = dw * rstd * gg.w + bb4.w;
    float4 o4 = {o0, o1, o2, o3};
    *(float4*)(y + off) = o4;
    u16x4 ob = {f2bf(o0), f2bf(o1), f2bf(o2), f2bf(o3)};
    *(u16x4*)(yb + off) = ob;
}

// -------------------------------------------------- entity pooling (2-phase)
__global__ __launch_bounds__(256)
void pool_partial_kernel(const float* __restrict__ h, float* __restrict__ partial)
{
    const int chunk = blockIdx.x, b = blockIdx.y;   // 11 chunks of 64 tokens
    const int d = threadIdx.x * 4;
    const float* p = h + ((size_t)b * TT + chunk * 64) * DD + d;
    float4 s = {0.f, 0.f, 0.f, 0.f};
    for (int t = 0; t < 64; ++t) {
        float4 v = *(const float4*)(p + (size_t)t * DD);
        s.x += v.x; s.y += v.y; s.z += v.z; s.w += v.w;
    }
    *(float4*)(partial + ((size_t)(b * 11 + chunk)) * 1024 + d) = s;
}

__global__ __launch_bounds__(256)
void pool_finish_kernel(const float* __restrict__ partial, const float* __restrict__ W_ent,
                        const float* __restrict__ b_ent, float* __restrict__ entities)
{
    const int b = blockIdx.x / 3, e = blockIdx.x % 3;
    const int c0 = (e == 0) ? 0 : (e == 1) ? 2 : 3;
    const int c1 = (e == 0) ? 2 : (e == 1) ? 3 : 11;
    const float invlen = (e == 0) ? (1.f/128.f) : (e == 1) ? (1.f/64.f) : (1.f/512.f);
    __shared__ float pooled[1024];
    __shared__ float part[8][32];
    const int tid = threadIdx.x;
    {
        const int d = tid * 4;
        float4 s = {0.f, 0.f, 0.f, 0.f};
        for (int c = c0; c < c1; ++c) {
            float4 v = *(const float4*)(partial + ((size_t)(b * 11 + c)) * 1024 + d);
            s.x += v.x; s.y += v.y; s.z += v.z; s.w += v.w;
        }
        pooled[d+0] = s.x * invlen; pooled[d+1] = s.y * invlen;
        pooled[d+2] = s.z * invlen; pooled[d+3] = s.w * invlen;
    }
    __syncthreads();
    const int g = tid >> 5, j = tid & 31;
    float s = 0.f;
    for (int d = g * 128; d < g * 128 + 128; ++d) s = fmaf(pooled[d], W_ent[d * 32 + j], s);
    part[g][j] = s;
    __syncthreads();
    if (tid < 32) {
        float s2 = b_ent[tid];
        for (int g2 = 0; g2 < 8; ++g2) s2 += part[g2][tid];
        entities[blockIdx.x * 32 + tid] = s2;
    }
}

// ------------------------- rule/entity selection (LDS-staged, wave-parallel)
__global__ __launch_bounds__(256)
void select_kernel(const float* __restrict__ entities, const float* __restrict__ rules,
                   const float* __restrict__ Wq_er, const float* __restrict__ Wk_er,
                   const float* __restrict__ Wq_es, const float* __restrict__ Wk_es,
                   int* __restrict__ slot_rule, float* __restrict__ gate)
{
    __shared__ float rules_s[4096];   // [k][r][64]
    __shared__ float Wq_er_s[2048];   // [64][32]
    __shared__ float Wq_es_s[4096];   // [k][64][16]
    __shared__ float Wk_er_s[1024];   // [32][32]
    __shared__ float Wk_es_s[512];    // [32][16]
    __shared__ float ent_s[768];      // [b][e][32]
    __shared__ float q_er_s[2048];    // [k][r][32]
    __shared__ float k_er_s[768];
    __shared__ float k_es_s[384];
    __shared__ float qes_s[32][16];
    __shared__ int   rsel_s[32];
    __shared__ int   sel_e[32];
    const int tid = threadIdx.x;
    for (int i = tid; i < 1024; i += 256) *(float4*)&rules_s[i*4] = *(const float4*)&rules[i*4];
    for (int i = tid; i < 512;  i += 256) *(float4*)&Wq_er_s[i*4] = *(const float4*)&Wq_er[i*4];
    for (int i = tid; i < 1024; i += 256) *(float4*)&Wq_es_s[i*4] = *(const float4*)&Wq_es[i*4];
    if (tid < 256) *(float4*)&Wk_er_s[tid*4] = *(const float4*)&Wk_er[tid*4];
    if (tid < 128) *(float4*)&Wk_es_s[tid*4] = *(const float4*)&Wk_es[tid*4];
    if (tid < 192) *(float4*)&ent_s[tid*4] = *(const float4*)&entities[tid*4];
    __syncthreads();
    for (int idx = tid; idx < 2048; idx += 256) {
        int k = idx >> 9, rem = idx & 511, r = rem >> 5, d = rem & 31;
        float s = 0.f;
        for (int hh = 0; hh < 64; ++hh)
            s = fmaf(rules_s[(k * 16 + r) * 64 + hh], Wq_er_s[hh * 32 + d], s);
        q_er_s[idx] = s;
    }
    for (int idx = tid; idx < 768; idx += 256) {
        int be = idx >> 5, d = idx & 31;
        float s = 0.f;
        for (int ss = 0; ss < 32; ++ss)
            s = fmaf(ent_s[be * 32 + ss], Wk_er_s[ss * 32 + d], s);
        k_er_s[idx] = s;
    }
    for (int idx = tid; idx < 384; idx += 256) {
        int be = idx >> 4, i = idx & 15;
        float s = 0.f;
        for (int ss = 0; ss < 32; ++ss)
            s = fmaf(ent_s[be * 32 + ss], Wk_es_s[ss * 16 + i], s);
        k_es_s[idx] = s;
    }
    __syncthreads();
    {
        const int pair = tid >> 3, slice = tid & 7;
        const int b = pair >> 2, k = pair & 3;
        float best = -1e30f; int bj = 48;
        for (int j = slice * 6; j < slice * 6 + 6; ++j) {
            const int r = j / 3, e = j - 3 * r;
            const float* qp = &q_er_s[(k * 16 + r) * 32];
            const float* kp = &k_er_s[(b * 3 + e) * 32];
            float s = 0.f;
            for (int d = 0; d < 32; ++d) s = fmaf(qp[d], kp[d], s);
            s *= 0.17677669529663687f;   // 1/sqrt(32)
            if (s > best) { best = s; bj = j; }
        }
#pragma unroll
        for (int off = 1; off < 8; off <<= 1) {
            float os = __shfl_xor(best, off);
            int oj = __shfl_xor(bj, off);
            if (os > best || (os == best && oj < bj)) { best = os; bj = oj; }
        }
        if (slice == 0) { rsel_s[pair] = bj / 3; slot_rule[pair] = bj / 3; }
    }
    __syncthreads();
    {
        const int pair = tid >> 3, slice = tid & 7;
        const int k = pair & 3, rstar = rsel_s[pair];
#pragma unroll
        for (int ii = 0; ii < 2; ++ii) {
            const int i = slice * 2 + ii;
            float s = 0.f;
            for (int hh = 0; hh < 64; ++hh)
                s = fmaf(rules_s[(k * 16 + rstar) * 64 + hh], Wq_es_s[(k * 64 + hh) * 16 + i], s);
            qes_s[pair][i] = s;
        }
    }
    __syncthreads();
    if ((tid & 7) == 0) {
        const int pair = tid >> 3, b = pair >> 2;
        float best2 = -1e30f; int ei = 0;
        for (int e = 0; e < 3; ++e) {
            float s = 0.f;
            for (int i = 0; i < 16; ++i) s = fmaf(qes_s[pair][i], k_es_s[(b * 3 + e) * 16 + i], s);
            s *= 0.25f;   // 1/sqrt(16)
            if (s > best2) { best2 = s; ei = e; }
        }
        sel_e[pair] = ei;
    }
    __syncthreads();
    if (tid < 24) {
        const int b = tid / 3, e = tid % 3;
        float g = 0.f;
        for (int k = 0; k < 4; ++k) g += (sel_e[b * 4 + k] == e) ? 1.f : 0.f;
        gate[b * 3 + e] = g;
    }
}

// ----------------------------- batched fp32 [R][C] -> bf16 [C][R] transposes
__device__ __forceinline__ void transpose_tile(const float* __restrict__ in,
                                               u16* __restrict__ out,
                                               int R, int C, int tr, int tc)
{
    __shared__ float tile[32][33];
    const int tx = threadIdx.x & 31, ty = threadIdx.x >> 5;
    const int c0 = tc * 32, r0 = tr * 32;
#pragma unroll
    for (int j = 0; j < 4; ++j)
        tile[ty + j * 8][tx] = in[(size_t)(r0 + ty + j * 8) * C + c0 + tx];
    __syncthreads();
#pragma unroll
    for (int j = 0; j < 4; ++j)
        out[(size_t)(c0 + ty + j * 8) * R + r0 + tx] = f2bf(tile[tx][ty + j * 8]);
}

// Wo [64x1024] -> WoT4 [1024][256] = WoT replicated 4x along columns
__device__ __forceinline__ void transpose_tile_rep4(const float* __restrict__ in,
                                                    u16* __restrict__ out,
                                                    int tr, int tc)
{
    __shared__ float tile[32][33];
    const int tx = threadIdx.x & 31, ty = threadIdx.x >> 5;
    const int c0 = tc * 32, r0 = tr * 32;   // in is 64 x 1024
#pragma unroll
    for (int j = 0; j < 4; ++j)
        tile[ty + j * 8][tx] = in[(size_t)(r0 + ty + j * 8) * 1024 + c0 + tx];
    __syncthreads();
#pragma unroll
    for (int j = 0; j < 4; ++j) {
        const u16 v = f2bf(tile[tx][ty + j * 8]);
        u16* o = out + (size_t)(c0 + ty + j * 8) * 256 + r0 + tx;
#pragma unroll
        for (int rep = 0; rep < 4; ++rep) o[rep * 64] = v;
    }
}

// all 8 weight transposes in one launch (8256 blocks)
__global__ __launch_bounds__(256)
void transpose_all_kernel(const float* __restrict__ Wq, const float* __restrict__ Wk,
                          const float* __restrict__ Wv, const float* __restrict__ Wo,
                          const float* __restrict__ fc1w1, const float* __restrict__ fc2w2,
                          const float* __restrict__ fc1w2, const float* __restrict__ fc2w1,
                          u16* __restrict__ WqkvT, u16* __restrict__ WoT4,
                          u16* __restrict__ fc1w1T, u16* __restrict__ fc2w2T,
                          u16* __restrict__ fc1w2T, u16* __restrict__ fc2w1T)
{
    const int bid = blockIdx.x;
    if (bid < 3072) {
        const int m = bid >> 10, t = bid & 1023;
        const float* in = (m == 0) ? Wq : (m == 1) ? Wk : Wv;
        transpose_tile(in, WqkvT + (size_t)m * 1024 * 1024, 1024, 1024, t >> 5, t & 31);
    } else if (bid < 3136) {
        const int t = bid - 3072;
        transpose_tile_rep4(Wo, WoT4, t >> 5, t & 31);
    } else if (bid < 3648) {
        const int t = bid - 3136;
        transpose_tile(fc1w1, fc1w1T, 1024, 512, t >> 4, t & 15);
    } else if (bid < 4160) {
        const int t = bid - 3648;
        transpose_tile(fc2w2, fc2w2T, 512, 1024, t >> 5, t & 31);
    } else if (bid < 6208) {
        const int t = bid - 4160;
        transpose_tile(fc1w2, fc1w2T, 512, 4096, t >> 7, t & 127);
    } else {
        const int t = bid - 6208;
        transpose_tile(fc2w1, fc2w1T, 4096, 512, t >> 4, t & 15);
    }
}

// --------------- pipelined MFMA bf16 GEMM, 128xBN tile, 3-buf, 1D swz grid
template<int BN, int ACT, int OBF16, int RESB, int SWZ>
__global__ __launch_bounds__(256)
void gemm2(const u16* __restrict__ A, int lda, const u16* __restrict__ Bt, int ldb,
           void* C0, void* C1, int ldc, int M, int Ksub,
           const void* __restrict__ resid, const float* __restrict__ bias, float bscale,
           int gx, int gy)
{
    constexpr int MI = (BN == 128) ? 4 : 2;     // 16-row frags per wave
    constexpr int NLOAD = 2 + ((BN == 128) ? 2 : 1);
    __shared__ u16 As[3][128 * 32];
    __shared__ u16 Bs[3][BN * 32];
    const int tid = threadIdx.x;
    const int wid = tid >> 6, lane = tid & 63;
    const int bid = SWZ ? xcd_swz(blockIdx.x, gridDim.x) : (int)blockIdx.x;
    const int col = bid % gx;
    const int rem = bid / gx;
    const int row = rem % gy;
    const int z = rem / gy;
    const int row0 = row * 128, col0 = col * BN;
    const size_t koff = (size_t)z * Ksub;
    const int srA = wid * 32 + (lane >> 2);
    const int sc = (lane & 3) * 8;
    const u16* ag = A + (size_t)(row0 + srA) * lda + koff + sc;
    const int srB = (BN == 128) ? (wid * 32 + (lane >> 2)) : (wid * 16 + (lane >> 2));
    const u16* bg = Bt + (size_t)(col0 + srB) * ldb + koff + sc;
    const int nt = Ksub >> 5;

    auto STAGE = [&](int buf, int t) {
        const u16* a = ag + t * 32;
        const u16* b = bg + t * 32;
        gl2lds(a, &As[buf][wid * 1024]);
        gl2lds(a + (size_t)16 * lda, &As[buf][wid * 1024 + 512]);
        if constexpr (BN == 128) {
            gl2lds(b, &Bs[buf][wid * 1024]);
            gl2lds(b + (size_t)16 * ldb, &Bs[buf][wid * 1024 + 512]);
        } else {
            gl2lds(b, &Bs[buf][wid * 512]);
        }
    };

    f32x4 acc[MI][4];
#pragma unroll
    for (int i = 0; i < MI; ++i)
#pragma unroll
        for (int j = 0; j < 4; ++j) acc[i][j] = (f32x4){0.f, 0.f, 0.f, 0.f};

    const int fr = lane & 15, kb8 = (lane >> 4) * 8;
    const int wrbase = (BN == 128) ? (wid >> 1) * 64 : wid * 32;
    const int wcbase = (BN == 128) ? (wid & 1) * 64 : 0;
    const int paoff = (wrbase + fr) * 32 + kb8;
    const int pboff = (wcbase + fr) * 32 + kb8;

    STAGE(0, 0);
    if (nt > 1) STAGE(1, 1);
    for (int t = 0; t < nt; ++t) {
        if (t + 1 < nt) waitv<NLOAD>(); else waitv<0>();
        __builtin_amdgcn_s_barrier();
        asm volatile("" ::: "memory");
        const int buf = t % 3;
#pragma unroll
        for (int mi = 0; mi < MI; ++mi) {
            bf16x8 af = *(const bf16x8*)&As[buf][paoff + mi * 512];
#pragma unroll
            for (int ni = 0; ni < 4; ++ni) {
                bf16x8 bfv = *(const bf16x8*)&Bs[buf][pboff + ni * 512];
                acc[mi][ni] = __builtin_amdgcn_mfma_f32_16x16x32_bf16(af, bfv, acc[mi][ni], 0, 0, 0);
            }
        }
        if (t + 2 < nt) STAGE((t + 2) % 3, t + 2);
    }

    void* Cp = (z == 0) ? C0 : C1;
    const int fq4 = (lane >> 4) * 4;
#pragma unroll
    for (int mi = 0; mi < MI; ++mi) {
#pragma unroll
        for (int j = 0; j < 4; ++j) {
            const int rw = row0 + wrbase + mi * 16 + fq4 + j;
#pragma unroll
            for (int ni = 0; ni < 4; ++ni) {
                const int cl = col0 + wcbase + ni * 16 + fr;
                float v = acc[mi][ni][j];
                if (bias) v += bscale * bias[cl];
                if (ACT == 1) v = fmaxf(v, 0.f);
                else if (ACT == 2) v = gelu_fast(v);
                const size_t off = (size_t)rw * ldc + cl;
                if (OBF16) {
                    ((u16*)Cp)[off] = f2bf(v);
                } else {
                    if (resid) v += RESB ? bf2f(((const u16*)resid)[off])
                                         : ((const float*)resid)[off];
                    ((float*)Cp)[off] = v;
                }
            }
        }
    }
}

// ------------------------------------------- split-K reduce: relu + bf16 out
template<int NP>
__global__ __launch_bounds__(256)
void red_relu_kernel(const float* __restrict__ p0, const float* __restrict__ p1,
                     const float* __restrict__ p2, const float* __restrict__ p3,
                     u16* __restrict__ out)
{
    const int i = (blockIdx.x * 256 + threadIdx.x) * 4;
    float4 a = *(const float4*)(p0 + i);
    float4 b = *(const float4*)(p1 + i);
    a.x += b.x; a.y += b.y; a.z += b.z; a.w += b.w;
    if (NP == 4) {
        float4 c = *(const float4*)(p2 + i);
        float4 d = *(const float4*)(p3 + i);
        a.x += c.x + d.x; a.y += c.y + d.y; a.z += c.z + d.z; a.w += c.w + d.w;
    }
    u16x4 o = {f2bf(fmaxf(a.x, 0.f)), f2bf(fmaxf(a.y, 0.f)),
               f2bf(fmaxf(a.z, 0.f)), f2bf(fmaxf(a.w, 0.f))};
    *(u16x4*)(out + i) = o;
}

// -------- combine: hmid(bf16) = hidden + sum_slot AO_z @ Wo + 4*bo  (K=256)
__global__ __launch_bounds__(256)
void combine_mfma_kernel(const u16* __restrict__ AO, const u16* __restrict__ WoT4,
                         const float* __restrict__ hidden, const float* __restrict__ bo,
                         u16* __restrict__ hmid)
{
    __shared__ u16 As[3][128 * 32];
    __shared__ u16 Bs[3][128 * 32];
    const int tid = threadIdx.x;
    const int wid = tid >> 6, lane = tid & 63;
    const int bid = xcd_swz(blockIdx.x, gridDim.x);   // nwg = 352
    const int row0 = (bid >> 3) * 128, col0 = (bid & 7) * 128;
    const int srA = wid * 32 + (lane >> 2);
    const int sc = (lane & 3) * 8;
    const int arow0 = row0 + srA, arow1 = arow0 + 16;
    const int ab0 = arow0 / TT, at0 = arow0 - ab0 * TT;
    const int ab1 = arow1 / TT, at1 = arow1 - ab1 * TT;
    const u16* abase0 = AO + ((size_t)(ab0 * 4) * TT + at0) * 64 + sc;
    const u16* abase1 = AO + ((size_t)(ab1 * 4) * TT + at1) * 64 + sc;
    const u16* bg = WoT4 + (size_t)(col0 + srA) * 256 + sc;
    const int nt = 8;   // K=256, BK=32

    auto STAGE = [&](int buf, int t) {
        const int k0 = t * 32;
        const size_t delta = (size_t)(k0 >> 6) * (TT * 64) + (k0 & 63);
        gl2lds(abase0 + delta, &As[buf][wid * 1024]);
        gl2lds(abase1 + delta, &As[buf][wid * 1024 + 512]);
        gl2lds(bg + k0, &Bs[buf][wid * 1024]);
        gl2lds(bg + k0 + (size_t)16 * 256, &Bs[buf][wid * 1024 + 512]);
    };

    f32x4 acc[4][4];
#pragma unroll
    for (int i = 0; i < 4; ++i)
#pragma unroll
        for (int j = 0; j < 4; ++j) acc[i][j] = (f32x4){0.f, 0.f, 0.f, 0.f};
    const int fr = lane & 15, kb8 = (lane >> 4) * 8;
    const int wrbase = (wid >> 1) * 64, wcbase = (wid & 1) * 64;
    const int paoff = (wrbase + fr) * 32 + kb8;
    const int pboff = (wcbase + fr) * 32 + kb8;

    STAGE(0, 0);
    STAGE(1, 1);
    for (int t = 0; t < nt; ++t) {
        if (t + 1 < nt) waitv<4>(); else waitv<0>();
        __builtin_amdgcn_s_barrier();
        asm volatile("" ::: "memory");
        const int buf = t % 3;
#pragma unroll
        for (int mi = 0; mi < 4; ++mi) {
            bf16x8 af = *(const bf16x8*)&As[buf][paoff + mi * 512];
#pragma unroll
            for (int ni = 0; ni < 4; ++ni) {
                bf16x8 bfv = *(const bf16x8*)&Bs[buf][pboff + ni * 512];
                acc[mi][ni] = __builtin_amdgcn_mfma_f32_16x16x32_bf16(af, bfv, acc[mi][ni], 0, 0, 0);
            }
        }
        if (t + 2 < nt) STAGE((t + 2) % 3, t + 2);
    }

    const int fq4 = (lane >> 4) * 4;
#pragma unroll
    for (int mi = 0; mi < 4; ++mi)
#pragma unroll
        for (int j = 0; j < 4; ++j) {
            const int rw = row0 + wrbase + mi * 16 + fq4 + j;
#pragma unroll
            for (int ni = 0; ni < 4; ++ni) {
                const int cl = col0 + wcbase + ni * 16 + fr;
                const size_t off = (size_t)rw * DD + cl;
                float v = acc[mi][ni][j] + 4.f * bo[cl] + hidden[off];
                hmid[off] = f2bf(v);
            }
        }
}

// ---------------- fused QKV projection: one block computes Q,K and V^T tiles
__global__ __launch_bounds__(256)
void qkv3_mfma_kernel(const u16* __restrict__ hb, const u16* __restrict__ WqkvT,
                      const float* __restrict__ bq, const float* __restrict__ bk,
                      const float* __restrict__ bv, const int* __restrict__ slot_rule,
                      const float* __restrict__ gatep,
                      u16* __restrict__ Qb, u16* __restrict__ Kb, u16* __restrict__ VT)
{
    const int bid = xcd_swz(blockIdx.x, gridDim.x);
    const int slot = bid & 3;
    const int mt = (bid >> 2) % 11;
    const int b = (bid >> 2) / 11;
    const int z = b * 4 + slot;
    const int r = slot_rule[z];
    const float gv = gatep[b * 3 + ((mt < 2) ? 0 : (mt < 3) ? 1 : 2)];
    __shared__ u16 As[3][64 * 32];
    __shared__ u16 Bs[3][3][64 * 32];
    const int tid = threadIdx.x;
    const int w = tid >> 6, lane = tid & 63;
    const u16* ag = hb + ((size_t)b * TT + mt * 64 + (tid >> 2)) * DD + (tid & 3) * 8;
    const u16* bg0 = WqkvT + (size_t)0 * DD * DD + (size_t)(r * 64 + (tid >> 2)) * DD + (tid & 3) * 8;
    const u16* bg1 = WqkvT + (size_t)1 * DD * DD + (size_t)(r * 64 + (tid >> 2)) * DD + (tid & 3) * 8;
    const u16* bg2 = WqkvT + (size_t)2 * DD * DD + (size_t)(r * 64 + (tid >> 2)) * DD + (tid & 3) * 8;
    auto STAGE = [&](int buf, int t) {
        gl2lds(ag  + t * 32, &As[buf][w * 512]);
        gl2lds(bg0 + t * 32, &Bs[buf][0][w * 512]);
        gl2lds(bg1 + t * 32, &Bs[buf][1][w * 512]);
        gl2lds(bg2 + t * 32, &Bs[buf][2][w * 512]);
    };
    f32x4 accq[4], acck[4], accv[4];
#pragma unroll
    for (int i = 0; i < 4; ++i) {
        accq[i] = (f32x4){0.f, 0.f, 0.f, 0.f};
        acck[i] = (f32x4){0.f, 0.f, 0.f, 0.f};
        accv[i] = (f32x4){0.f, 0.f, 0.f, 0.f};
    }
    const int fr = lane & 15, kb8 = (lane >> 4) * 8;
    const int paoff = (w * 16 + fr) * 32 + kb8;
    const int nt = 32;
    STAGE(0, 0);
    STAGE(1, 1);
    for (int t = 0; t < nt; ++t) {
        if (t + 1 < nt) waitv<4>(); else waitv<0>();
        __builtin_amdgcn_s_barrier();
        asm volatile("" ::: "memory");
        const int buf = t % 3;
        bf16x8 af = *(const bf16x8*)&As[buf][paoff];
#pragma unroll
        for (int ni = 0; ni < 4; ++ni) {
            const int boff = (ni * 16 + fr) * 32 + kb8;
            bf16x8 bq8 = *(const bf16x8*)&Bs[buf][0][boff];
            bf16x8 bk8 = *(const bf16x8*)&Bs[buf][1][boff];
            bf16x8 bv8 = *(const bf16x8*)&Bs[buf][2][boff];
            accq[ni] = __builtin_amdgcn_mfma_f32_16x16x32_bf16(af, bq8, accq[ni], 0, 0, 0);
            acck[ni] = __builtin_amdgcn_mfma_f32_16x16x32_bf16(af, bk8, acck[ni], 0, 0, 0);
            accv[ni] = __builtin_amdgcn_mfma_f32_16x16x32_bf16(bv8, af, accv[ni], 0, 0, 0);
        }
        if (t + 2 < nt) STAGE((t + 2) % 3, t + 2);
    }
    const size_t bs = (size_t)z * TT;
    const int fq4 = (lane >> 4) * 4;
#pragma unroll
    for (int ni = 0; ni < 4; ++ni)
#pragma unroll
        for (int j = 0; j < 4; ++j) {
            const int row = mt * 64 + w * 16 + fq4 + j;
            const int col = ni * 16 + fr;
            Qb[(bs + row) * 64 + col] = f2bf((gv * accq[ni][j] + bq[r * 64 + col]) * 0.125f);
            Kb[(bs + row) * 64 + col] = f2bf(gv * acck[ni][j] + bk[r * 64 + col]);
            const int d = ni * 16 + fq4 + j;
            const int tt2 = mt * 64 + w * 16 + fr;
            VT[((size_t)z * 64 + d) * TT + tt2] = f2bf(gv * accv[ni][j] + bv[r * 64 + d]);
        }
}

// ----------------------------------------- MFMA bf16 flash attention / slot
__global__ __launch_bounds__(256)
void attn_mfma_kernel(const u16* __restrict__ Qb, const u16* __restrict__ Kb,
                      const u16* __restrict__ VT, const float* __restrict__ amask,
                      u16* __restrict__ AO)
{
    const int bid = xcd_swz(blockIdx.x, gridDim.x);
    const int slot = bid & 3;
    const int qt = (bid >> 2) % 11;
    const int b = (bid >> 2) / 11;
    const int z = b * 4 + slot;
    const size_t bs = (size_t)z * TT;
    const int tid = threadIdx.x;
    const int w = tid >> 6, lane = tid & 63;
    const int fr = lane & 15, g = lane >> 4;
    const int q0 = qt * 64 + w * 16;

    __shared__ u16 Ks[64 * 72];    // [key][d], stride 72
    __shared__ u16 VTs[64 * 72];   // [d][key]
    __shared__ u16 Ps[4][16 * 72]; // per-wave P tile [q][key]

    bf16x8 qa[2];
    qa[0] = *(const bf16x8*)(Qb + (bs + q0 + fr) * 64 + g * 8);
    qa[1] = *(const bf16x8*)(Qb + (bs + q0 + fr) * 64 + 32 + g * 8);

    float m_run[4], l_run[4];
    f32x4 oacc[4];
#pragma unroll
    for (int j = 0; j < 4; ++j) { m_run[j] = -1e30f; l_run[j] = 0.f; }
#pragma unroll
    for (int ni = 0; ni < 4; ++ni) oacc[ni] = (f32x4){0.f, 0.f, 0.f, 0.f};

    const float* mrow = amask + ((size_t)b * TT + q0 + g * 4) * TT;

    for (int kc = 0; kc < 11; ++kc) {
        const int kv0 = kc * 64;
        __syncthreads();
#pragma unroll
        for (int it = 0; it < 2; ++it) {
            const int idx = tid + it * 256;
            const int row = idx >> 3, ch = (idx & 7) * 8;
            *(u16x8*)&Ks[row * 72 + ch]  = *(const u16x8*)(Kb + (bs + kv0 + row) * 64 + ch);
            *(u16x8*)&VTs[row * 72 + ch] = *(const u16x8*)(VT + ((size_t)z * 64 + row) * TT + kv0 + ch);
        }
        __syncthreads();
        f32x4 sacc[4];
#pragma unroll
        for (int ni = 0; ni < 4; ++ni) sacc[ni] = (f32x4){0.f, 0.f, 0.f, 0.f};
#pragma unroll
        for (int c = 0; c < 2; ++c)
#pragma unroll
            for (int ni = 0; ni < 4; ++ni) {
                bf16x8 bf = *(const bf16x8*)&Ks[(ni * 16 + fr) * 72 + c * 32 + g * 8];
                sacc[ni] = __builtin_amdgcn_mfma_f32_16x16x32_bf16(qa[c], bf, sacc[ni], 0, 0, 0);
            }
        float mloc[4] = {-1e30f, -1e30f, -1e30f, -1e30f};
#pragma unroll
        for (int ni = 0; ni < 4; ++ni)
#pragma unroll
            for (int j = 0; j < 4; ++j) {
                float s = sacc[ni][j] + mrow[(size_t)j * TT + kv0 + ni * 16 + fr];
                sacc[ni][j] = s;
                mloc[j] = fmaxf(mloc[j], s);
            }
#pragma unroll
        for (int o = 1; o < 16; o <<= 1)
#pragma unroll
            for (int j = 0; j < 4; ++j) mloc[j] = fmaxf(mloc[j], __shfl_xor(mloc[j], o));
        float fac[4], lsum[4];
#pragma unroll
        for (int j = 0; j < 4; ++j) {
            const float mn = fmaxf(m_run[j], mloc[j]);
            fac[j] = __expf(m_run[j] - mn);
            m_run[j] = mn;
            lsum[j] = 0.f;
        }
#pragma unroll
        for (int ni = 0; ni < 4; ++ni)
#pragma unroll
            for (int j = 0; j < 4; ++j) {
                const float p = __expf(sacc[ni][j] - m_run[j]);
                lsum[j] += p;
                Ps[w][(g * 4 + j) * 72 + ni * 16 + fr] = f2bf(p);
            }
#pragma unroll
        for (int o = 1; o < 16; o <<= 1)
#pragma unroll
            for (int j = 0; j < 4; ++j) lsum[j] += __shfl_xor(lsum[j], o);
#pragma unroll
        for (int j = 0; j < 4; ++j) l_run[j] = l_run[j] * fac[j] + lsum[j];
#pragma unroll
        for (int ni = 0; ni < 4; ++ni)
#pragma unroll
            for (int j = 0; j < 4; ++j) oacc[ni][j] *= fac[j];
#pragma unroll
        for (int c = 0; c < 2; ++c) {
            bf16x8 paf = *(const bf16x8*)&Ps[w][fr * 72 + c * 32 + g * 8];
#pragma unroll
            for (int ni = 0; ni < 4; ++ni) {
                bf16x8 vf = *(const bf16x8*)&VTs[(ni * 16 + fr) * 72 + c * 32 + g * 8];
                oacc[ni] = __builtin_amdgcn_mfma_f32_16x16x32_bf16(paf, vf, oacc[ni], 0, 0, 0);
            }
        }
    }
#pragma unroll
    for (int j = 0; j < 4; ++j) {
        const float inv = 1.f / l_run[j];
        const int t = q0 + g * 4 + j;
#pragma unroll
        for (int ni = 0; ni < 4; ++ni)
            AO[(bs + t) * 64 + ni * 16 + fr] = f2bf(oacc[ni][j] * inv);
    }
}

// ---------------------------------------------------------------- launcher
extern "C" void kernel_launch(void* const* d_in, const int* in_sizes, int n_in,
                              void* d_out, int out_size, void* d_ws, size_t ws_size,
                              hipStream_t stream)
{
    const float* hidden = (const float*)d_in[0];
    const float* amask  = (const float*)d_in[1];
    const float* rules  = (const float*)d_in[2];
    const float* W_ent  = (const float*)d_in[3];
    const float* b_ent  = (const float*)d_in[4];
    const float* Wq_er  = (const float*)d_in[5];
    const float* Wk_er  = (const float*)d_in[6];
    const float* Wq_es  = (const float*)d_in[7];
    const float* Wk_es  = (const float*)d_in[8];
    const float* Wq     = (const float*)d_in[9];
    const float* bq     = (const float*)d_in[10];
    const float* Wk     = (const float*)d_in[11];
    const float* bk     = (const float*)d_in[12];
    const float* Wv     = (const float*)d_in[13];
    const float* bv     = (const float*)d_in[14];
    const float* Wo     = (const float*)d_in[15];
    const float* bo     = (const float*)d_in[16];
    const float* ln1_g  = (const float*)d_in[17];
    const float* ln1_b  = (const float*)d_in[18];
    const float* ln2_g  = (const float*)d_in[19];
    const float* ln2_b  = (const float*)d_in[20];
    const float* fc1_w1 = (const float*)d_in[21];
    const float* fc1_w2 = (const float*)d_in[22];
    const float* fc2_w1 = (const float*)d_in[23];
    const float* fc2_w2 = (const float*)d_in[24];

    char* ws = (char*)d_ws;
    // -------- workspace map (bytes); max end 92,274,688 <= proven 92,278,016
    float* h      = (float*)(ws + 0);              // 23,068,672 [ln1..pool_partial]
    u16*   x1     = (u16*)(ws + 0);                //  5,767,168 [G1..G2]
    float* g3p0   = (float*)(ws + 0);              // 11,534,336 [G3..G3red] (over dead x1)
    u16*   fc1w2T = (u16*)(ws + 11534336);         //  4,194,304 [transpose..G2] (in dead h)
    u16*   x3b    = (u16*)(ws + 11534336);         //  5,767,168 [G3red..G4] (over dead fc1w2T/fc2w1T)
    u16*   fc2w1T = (u16*)(ws + 15728640);         //  4,194,304 [transpose..G3] (in dead h)
    u16*   fc2w2T = (u16*)(ws + 19922944);         //  1,048,576 [transpose..G4] (in dead h)
    u16*   fc1w1T = (u16*)(ws + 20971520);         //  1,048,576 [transpose..G1] (in dead h)
    u16*   WoT4   = (u16*)(ws + 22020096);         //    524,288 [transpose..combine] (in dead h)
    u16*   hmid   = (u16*)(ws + 23068672);         // 11,534,336 bf16 [combine..G4]
    float* g3p1   = (float*)(ws + 34603008);       // 11,534,336 [G3..G3red]
    u16*   hb     = (u16*)(ws + 46137344);         // 11,534,336 bf16 LN1 out [ln1..qkv]
    u16*   xln2   = (u16*)(ws + 46137344);         //   (reuse)  [ln2..G1]
    u16*   x2     = (u16*)(ws + 46137344);         // 46,137,344 full [G2..G3]
    u16*   Qb     = (u16*)(ws + 57671680);         //  2,883,584 [qkv..attn]
    u16*   Kb     = (u16*)(ws + 60555264);         //  2,883,584
    u16*   VT     = (u16*)(ws + 66322432);         //  2,883,584
    u16*   AO     = (u16*)(ws + 69206016);         //  2,883,584 [attn..combine]
    float* part   = (float*)(ws + 69206016);       //    360,448 (dead before AO)
    float* ent    = (float*)(ws + 80740352);       //      3,072 [pool_finish..select]
    float* gate   = (float*)(ws + 80743424);       //        128 [select..qkv3]
    int*   srule  = (int*)(ws + 80743552);         //        128 [select..qkv3]
    u16*   WqkvT  = (u16*)(ws + 80743680);         //  6,291,456 [transpose..qkv3]
    float* out    = (float*)d_out;

    // --- LN1 (dual fp32+bf16 out) + selection path
    ln1_dual_kernel<<<BT, 256, 0, stream>>>(hidden, ln1_g, ln1_b, h, hb);
    pool_partial_kernel<<<dim3(11, 8), 256, 0, stream>>>(h, part);
    pool_finish_kernel<<<24, 256, 0, stream>>>(part, W_ent, b_ent, ent);
    select_kernel<<<1, 256, 0, stream>>>(ent, rules, Wq_er, Wk_er, Wq_es, Wk_es, srule, gate);

    // --- all weight transposes in one launch (targets live in dead h)
    transpose_all_kernel<<<8256, 256, 0, stream>>>(Wq, Wk, Wv, Wo, fc1_w1, fc2_w2,
                                                   fc1_w2, fc2_w1,
                                                   WqkvT, WoT4, fc1w1T, fc2w2T,
                                                   fc1w2T, fc2w1T);

    // --- fused QKV (MFMA; gate applied in epilogue; writes Q, K, V^T)
    qkv3_mfma_kernel<<<352, 256, 0, stream>>>(hb, WqkvT, bq, bk, bv, srule, gate,
                                              Qb, Kb, VT);

    // --- attention (MFMA); XCD-swizzled so each XCD owns one batch b
    attn_mfma_kernel<<<352, 256, 0, stream>>>(Qb, Kb, VT, amask, AO);

    // --- combine: hmid(bf16) = hidden + sum_slot AO @ Wo + 4*bo (K=256 GEMM)
    combine_mfma_kernel<<<352, 256, 0, stream>>>(AO, WoT4, hidden, bo, hmid);

    // --- LN2 (bf16 in -> bf16 out)
    ln_kernel<1, 1><<<BT, 256, 0, stream>>>(hmid, ln2_g, ln2_b, xln2);

    // --- G1: x1 = relu(xln2 @ fc1w1T^T)  (fused relu->bf16), swizzled
    gemm2<64, 1, 1, 0, 1><<<352, 256, 0, stream>>>(
        xln2, 1024, fc1w1T, 1024, x1, nullptr, 512, BT, 1024,
        nullptr, nullptr, 0.f, 8, 44);

    // --- G2: x2 = gelu(x1 @ fc1w2T^T), full M; natural order pins B cols/XCD
    gemm2<128, 2, 1, 0, 0><<<1408, 256, 0, stream>>>(
        x1, 512, fc1w2T, 512, x2, nullptr, 4096, BT, 512,
        nullptr, nullptr, 0.f, 32, 44);

    // --- G3: split-K 2 fp32 partials, full M, swizzled
    gemm2<64, 0, 0, 0, 1><<<704, 256, 0, stream>>>(
        x2, 4096, fc2w1T, 4096, g3p0, g3p1, 512, BT, 2048,
        nullptr, nullptr, 0.f, 8, 44);
    red_relu_kernel<2><<<2816, 256, 0, stream>>>(g3p0, g3p1, nullptr, nullptr, x3b);

    // --- G4: out = hmid(bf16) + x3b @ fc2w2T^T, swizzled
    gemm2<64, 0, 0, 1, 1><<<704, 256, 0, stream>>>(
        x3b, 512, fc2w2T, 512, out, nullptr, 1024, BT, 512,
        hmid, nullptr, 0.f, 16, 44);
}

// Round 14
// 240.671 us; speedup vs baseline: 1.0174x; 1.0174x over previous
//
#include <hip/hip_runtime.h>
#include <hip/hip_bf16.h>
#include <math.h>

// Problem constants
#define BB 8
#define TT 704
#define DD 1024
#define RR 16
#define KK 4
#define HDH 64
#define BT (BB*TT)   // 5632

typedef unsigned short u16;
typedef __attribute__((ext_vector_type(4))) float f32x4;
typedef __attribute__((ext_vector_type(8))) short bf16x8;
typedef __attribute__((ext_vector_type(4))) unsigned short u16x4;
typedef __attribute__((ext_vector_type(8))) unsigned short u16x8;

__device__ __forceinline__ u16 f2bf(float f) {
    union { float f; unsigned int u; } cv; cv.f = f;
    unsigned int u = cv.u;
    unsigned int r = (u + 0x7fffu + ((u >> 16) & 1u)) >> 16;
    return (u16)r;
}

__device__ __forceinline__ float bf2f(u16 v) {
    union { unsigned int u; float f; } cv; cv.u = ((unsigned int)v) << 16;
    return cv.f;
}

__device__ __forceinline__ void gl2lds(const u16* g, u16* l) {
    __builtin_amdgcn_global_load_lds(
        (const __attribute__((address_space(1))) void*)g,
        (__attribute__((address_space(3))) void*)l, 16, 0, 0);
}

template<int N> __device__ __forceinline__ void waitv() {
    if constexpr (N == 0) asm volatile("s_waitcnt vmcnt(0)" ::: "memory");
    else if constexpr (N == 2) asm volatile("s_waitcnt vmcnt(2)" ::: "memory");
    else if constexpr (N == 3) asm volatile("s_waitcnt vmcnt(3)" ::: "memory");
    else asm volatile("s_waitcnt vmcnt(4)" ::: "memory");
}

// XCD-chunked swizzle: physical d -> logical bid so that each XCD (d%8) gets
// a CONTIGUOUS chunk of logical block ids (L2 locality). Requires nwg%8==0.
__device__ __forceinline__ int xcd_swz(int d, int nwg) {
    return (d & 7) * (nwg >> 3) + (d >> 3);
}

// ---------------------------------------------------------- LayerNorm (LN2)
template<int OBF16, int IBF16>
__global__ __launch_bounds__(256)
void ln_kernel(const void* __restrict__ xv, const float* __restrict__ g,
               const float* __restrict__ be, void* __restrict__ yv)
{
    const int row = blockIdx.x;
    const int tid = threadIdx.x;
    __shared__ float sbuf[4];
    const size_t off = (size_t)row * DD + tid * 4;
    float4 v;
    if (IBF16) {
        u16x4 xb = *(const u16x4*)((const u16*)xv + off);
        v.x = bf2f(xb[0]); v.y = bf2f(xb[1]); v.z = bf2f(xb[2]); v.w = bf2f(xb[3]);
    } else {
        v = *(const float4*)((const float*)xv + off);
    }
    float s = v.x + v.y + v.z + v.w;
#pragma unroll
    for (int o = 32; o; o >>= 1) s += __shfl_xor(s, o);
    if ((tid & 63) == 0) sbuf[tid >> 6] = s;
    __syncthreads();
    float mean = (sbuf[0] + sbuf[1] + sbuf[2] + sbuf[3]) * (1.f / 1024.f);
    float dx = v.x - mean, dy = v.y - mean, dz = v.z - mean, dw = v.w - mean;
    float q = dx*dx + dy*dy + dz*dz + dw*dw;
    __syncthreads();
#pragma unroll
    for (int o = 32; o; o >>= 1) q += __shfl_xor(q, o);
    if ((tid & 63) == 0) sbuf[tid >> 6] = q;
    __syncthreads();
    float var = (sbuf[0] + sbuf[1] + sbuf[2] + sbuf[3]) * (1.f / 1024.f);
    float rstd = rsqrtf(var + 1e-5f);
    float4 gg = *(const float4*)(g + tid * 4);
    float4 bb4 = *(const float4*)(be + tid * 4);
    float o0 = dx * rstd * gg.x + bb4.x;
    float o1 = dy * rstd * gg.y + bb4.y;
    float o2 = dz * rstd * gg.z + bb4.z;
    float o3 = dw * rstd * gg.w + bb4.w;
    if (OBF16) {
        u16x4 o4 = {f2bf(o0), f2bf(o1), f2bf(o2), f2bf(o3)};
        *(u16x4*)((u16*)yv + off) = o4;
    } else {
        float4 o4 = {o0, o1, o2, o3};
        *(float4*)((float*)yv + off) = o4;
    }
}

// ------------------------------- LN1: writes fp32 (pool path) + bf16 (GEMMs)
__global__ __launch_bounds__(256)
void ln1_dual_kernel(const float* __restrict__ x, const float* __restrict__ g,
                     const float* __restrict__ be, float* __restrict__ y,
                     u16* __restrict__ yb)
{
    const int row = blockIdx.x;
    const int tid = threadIdx.x;
    __shared__ float sbuf[4];
    const size_t off = (size_t)row * DD + tid * 4;
    float4 v = *(const float4*)(x + off);
    float s = v.x + v.y + v.z + v.w;
#pragma unroll
    for (int o = 32; o; o >>= 1) s += __shfl_xor(s, o);
    if ((tid & 63) == 0) sbuf[tid >> 6] = s;
    __syncthreads();
    float mean = (sbuf[0] + sbuf[1] + sbuf[2] + sbuf[3]) * (1.f / 1024.f);
    float dx = v.x - mean, dy = v.y - mean, dz = v.z - mean, dw = v.w - mean;
    float q = dx*dx + dy*dy + dz*dz + dw*dw;
    __syncthreads();
#pragma unroll
    for (int o = 32; o; o >>= 1) q += __shfl_xor(q, o);
    if ((tid & 63) == 0) sbuf[tid >> 6] = q;
    __syncthreads();
    float var = (sbuf[0] + sbuf[1] + sbuf[2] + sbuf[3]) * (1.f / 1024.f);
    float rstd = rsqrtf(var + 1e-5f);
    float4 gg = *(const float4*)(g + tid * 4);
    float4 bb4 = *(const float4*)(be + tid * 4);
    float o0 = dx * rstd * gg.x + bb4.x;
    float o1 = dy * rstd * gg.y + bb4.y;
    float o2 = dz * rstd * gg.z + bb4.z;
    float o3 = dw * rstd * gg.w + bb4.w;
    float4 o4 = {o0, o1, o2, o3};
    *(float4*)(y + off) = o4;
    u16x4 ob = {f2bf(o0), f2bf(o1), f2bf(o2), f2bf(o3)};
    *(u16x4*)(yb + off) = ob;
}

// -------------------------------------------------- entity pooling (2-phase)
__global__ __launch_bounds__(256)
void pool_partial_kernel(const float* __restrict__ h, float* __restrict__ partial)
{
    const int chunk = blockIdx.x, b = blockIdx.y;   // 11 chunks of 64 tokens
    const int d = threadIdx.x * 4;
    const float* p = h + ((size_t)b * TT + chunk * 64) * DD + d;
    float4 s = {0.f, 0.f, 0.f, 0.f};
    for (int t = 0; t < 64; ++t) {
        float4 v = *(const float4*)(p + (size_t)t * DD);
        s.x += v.x; s.y += v.y; s.z += v.z; s.w += v.w;
    }
    *(float4*)(partial + ((size_t)(b * 11 + chunk)) * 1024 + d) = s;
}

__global__ __launch_bounds__(256)
void pool_finish_kernel(const float* __restrict__ partial, const float* __restrict__ W_ent,
                        const float* __restrict__ b_ent, float* __restrict__ entities)
{
    const int b = blockIdx.x / 3, e = blockIdx.x % 3;
    const int c0 = (e == 0) ? 0 : (e == 1) ? 2 : 3;
    const int c1 = (e == 0) ? 2 : (e == 1) ? 3 : 11;
    const float invlen = (e == 0) ? (1.f/128.f) : (e == 1) ? (1.f/64.f) : (1.f/512.f);
    __shared__ float pooled[1024];
    __shared__ float part[8][32];
    const int tid = threadIdx.x;
    {
        const int d = tid * 4;
        float4 s = {0.f, 0.f, 0.f, 0.f};
        for (int c = c0; c < c1; ++c) {
            float4 v = *(const float4*)(partial + ((size_t)(b * 11 + c)) * 1024 + d);
            s.x += v.x; s.y += v.y; s.z += v.z; s.w += v.w;
        }
        pooled[d+0] = s.x * invlen; pooled[d+1] = s.y * invlen;
        pooled[d+2] = s.z * invlen; pooled[d+3] = s.w * invlen;
    }
    __syncthreads();
    const int g = tid >> 5, j = tid & 31;
    float s = 0.f;
    for (int d = g * 128; d < g * 128 + 128; ++d) s = fmaf(pooled[d], W_ent[d * 32 + j], s);
    part[g][j] = s;
    __syncthreads();
    if (tid < 32) {
        float s2 = b_ent[tid];
        for (int g2 = 0; g2 < 8; ++g2) s2 += part[g2][tid];
        entities[blockIdx.x * 32 + tid] = s2;
    }
}

// ------------------------- rule/entity selection (LDS-staged, wave-parallel)
__global__ __launch_bounds__(256)
void select_kernel(const float* __restrict__ entities, const float* __restrict__ rules,
                   const float* __restrict__ Wq_er, const float* __restrict__ Wk_er,
                   const float* __restrict__ Wq_es, const float* __restrict__ Wk_es,
                   int* __restrict__ slot_rule, float* __restrict__ gate)
{
    __shared__ float rules_s[4096];   // [k][r][64]
    __shared__ float Wq_er_s[2048];   // [64][32]
    __shared__ float Wq_es_s[4096];   // [k][64][16]
    __shared__ float Wk_er_s[1024];   // [32][32]
    __shared__ float Wk_es_s[512];    // [32][16]
    __shared__ float ent_s[768];      // [b][e][32]
    __shared__ float q_er_s[2048];    // [k][r][32]
    __shared__ float k_er_s[768];
    __shared__ float k_es_s[384];
    __shared__ float qes_s[32][16];
    __shared__ int   rsel_s[32];
    __shared__ int   sel_e[32];
    const int tid = threadIdx.x;
    for (int i = tid; i < 1024; i += 256) *(float4*)&rules_s[i*4] = *(const float4*)&rules[i*4];
    for (int i = tid; i < 512;  i += 256) *(float4*)&Wq_er_s[i*4] = *(const float4*)&Wq_er[i*4];
    for (int i = tid; i < 1024; i += 256) *(float4*)&Wq_es_s[i*4] = *(const float4*)&Wq_es[i*4];
    if (tid < 256) *(float4*)&Wk_er_s[tid*4] = *(const float4*)&Wk_er[tid*4];
    if (tid < 128) *(float4*)&Wk_es_s[tid*4] = *(const float4*)&Wk_es[tid*4];
    if (tid < 192) *(float4*)&ent_s[tid*4] = *(const float4*)&entities[tid*4];
    __syncthreads();
    for (int idx = tid; idx < 2048; idx += 256) {
        int k = idx >> 9, rem = idx & 511, r = rem >> 5, d = rem & 31;
        float s = 0.f;
        for (int hh = 0; hh < 64; ++hh)
            s = fmaf(rules_s[(k * 16 + r) * 64 + hh], Wq_er_s[hh * 32 + d], s);
        q_er_s[idx] = s;
    }
    for (int idx = tid; idx < 768; idx += 256) {
        int be = idx >> 5, d = idx & 31;
        float s = 0.f;
        for (int ss = 0; ss < 32; ++ss)
            s = fmaf(ent_s[be * 32 + ss], Wk_er_s[ss * 32 + d], s);
        k_er_s[idx] = s;
    }
    for (int idx = tid; idx < 384; idx += 256) {
        int be = idx >> 4, i = idx & 15;
        float s = 0.f;
        for (int ss = 0; ss < 32; ++ss)
            s = fmaf(ent_s[be * 32 + ss], Wk_es_s[ss * 16 + i], s);
        k_es_s[idx] = s;
    }
    __syncthreads();
    {
        const int pair = tid >> 3, slice = tid & 7;
        const int b = pair >> 2, k = pair & 3;
        float best = -1e30f; int bj = 48;
        for (int j = slice * 6; j < slice * 6 + 6; ++j) {
            const int r = j / 3, e = j - 3 * r;
            const float* qp = &q_er_s[(k * 16 + r) * 32];
            const float* kp = &k_er_s[(b * 3 + e) * 32];
            float s = 0.f;
            for (int d = 0; d < 32; ++d) s = fmaf(qp[d], kp[d], s);
            s *= 0.17677669529663687f;   // 1/sqrt(32)
            if (s > best) { best = s; bj = j; }
        }
#pragma unroll
        for (int off = 1; off < 8; off <<= 1) {
            float os = __shfl_xor(best, off);
            int oj = __shfl_xor(bj, off);
            if (os > best || (os == best && oj < bj)) { best = os; bj = oj; }
        }
        if (slice == 0) { rsel_s[pair] = bj / 3; slot_rule[pair] = bj / 3; }
    }
    __syncthreads();
    {
        const int pair = tid >> 3, slice = tid & 7;
        const int k = pair & 3, rstar = rsel_s[pair];
#pragma unroll
        for (int ii = 0; ii < 2; ++ii) {
            const int i = slice * 2 + ii;
            float s = 0.f;
            for (int hh = 0; hh < 64; ++hh)
                s = fmaf(rules_s[(k * 16 + rstar) * 64 + hh], Wq_es_s[(k * 64 + hh) * 16 + i], s);
            qes_s[pair][i] = s;
        }
    }
    __syncthreads();
    if ((tid & 7) == 0) {
        const int pair = tid >> 3, b = pair >> 2;
        float best2 = -1e30f; int ei = 0;
        for (int e = 0; e < 3; ++e) {
            float s = 0.f;
            for (int i = 0; i < 16; ++i) s = fmaf(qes_s[pair][i], k_es_s[(b * 3 + e) * 16 + i], s);
            s *= 0.25f;   // 1/sqrt(16)
            if (s > best2) { best2 = s; ei = e; }
        }
        sel_e[pair] = ei;
    }
    __syncthreads();
    if (tid < 24) {
        const int b = tid / 3, e = tid % 3;
        float g = 0.f;
        for (int k = 0; k < 4; ++k) g += (sel_e[b * 4 + k] == e) ? 1.f : 0.f;
        gate[b * 3 + e] = g;
    }
}

// ----------------------------- batched fp32 [R][C] -> bf16 [C][R] transposes
__device__ __forceinline__ void transpose_tile(const float* __restrict__ in,
                                               u16* __restrict__ out,
                                               int R, int C, int tr, int tc)
{
    __shared__ float tile[32][33];
    const int tx = threadIdx.x & 31, ty = threadIdx.x >> 5;
    const int c0 = tc * 32, r0 = tr * 32;
#pragma unroll
    for (int j = 0; j < 4; ++j)
        tile[ty + j * 8][tx] = in[(size_t)(r0 + ty + j * 8) * C + c0 + tx];
    __syncthreads();
#pragma unroll
    for (int j = 0; j < 4; ++j)
        out[(size_t)(c0 + ty + j * 8) * R + r0 + tx] = f2bf(tile[tx][ty + j * 8]);
}

// Wo [64x1024] -> WoT4 [1024][256] = WoT replicated 4x along columns
__device__ __forceinline__ void transpose_tile_rep4(const float* __restrict__ in,
                                                    u16* __restrict__ out,
                                                    int tr, int tc)
{
    __shared__ float tile[32][33];
    const int tx = threadIdx.x & 31, ty = threadIdx.x >> 5;
    const int c0 = tc * 32, r0 = tr * 32;   // in is 64 x 1024
#pragma unroll
    for (int j = 0; j < 4; ++j)
        tile[ty + j * 8][tx] = in[(size_t)(r0 + ty + j * 8) * 1024 + c0 + tx];
    __syncthreads();
#pragma unroll
    for (int j = 0; j < 4; ++j) {
        const u16 v = f2bf(tile[tx][ty + j * 8]);
        u16* o = out + (size_t)(c0 + ty + j * 8) * 256 + r0 + tx;
#pragma unroll
        for (int rep = 0; rep < 4; ++rep) o[rep * 64] = v;
    }
}

// all 8 weight transposes in one launch (8256 blocks)
__global__ __launch_bounds__(256)
void transpose_all_kernel(const float* __restrict__ Wq, const float* __restrict__ Wk,
                          const float* __restrict__ Wv, const float* __restrict__ Wo,
                          const float* __restrict__ fc1w1, const float* __restrict__ fc2w2,
                          const float* __restrict__ fc1w2, const float* __restrict__ fc2w1,
                          u16* __restrict__ WqkvT, u16* __restrict__ WoT4,
                          u16* __restrict__ fc1w1T, u16* __restrict__ fc2w2T,
                          u16* __restrict__ fc1w2T, u16* __restrict__ fc2w1T)
{
    const int bid = blockIdx.x;
    if (bid < 3072) {
        const int m = bid >> 10, t = bid & 1023;
        const float* in = (m == 0) ? Wq : (m == 1) ? Wk : Wv;
        transpose_tile(in, WqkvT + (size_t)m * 1024 * 1024, 1024, 1024, t >> 5, t & 31);
    } else if (bid < 3136) {
        const int t = bid - 3072;
        transpose_tile_rep4(Wo, WoT4, t >> 5, t & 31);
    } else if (bid < 3648) {
        const int t = bid - 3136;
        transpose_tile(fc1w1, fc1w1T, 1024, 512, t >> 4, t & 15);
    } else if (bid < 4160) {
        const int t = bid - 3648;
        transpose_tile(fc2w2, fc2w2T, 512, 1024, t >> 5, t & 31);
    } else if (bid < 6208) {
        const int t = bid - 4160;
        transpose_tile(fc1w2, fc1w2T, 512, 4096, t >> 7, t & 127);
    } else {
        const int t = bid - 6208;
        transpose_tile(fc2w1, fc2w1T, 4096, 512, t >> 4, t & 15);
    }
}

// --------------- pipelined MFMA bf16 GEMM, 128xBN tile, 3-buf, 1D swz grid
template<int BN, int ACT, int OBF16, int RESB, int SWZ>
__global__ __launch_bounds__(256)
void gemm2(const u16* __restrict__ A, int lda, const u16* __restrict__ Bt, int ldb,
           void* C0, void* C1, int ldc, int M, int Ksub,
           const void* __restrict__ resid, const float* __restrict__ bias, float bscale,
           int gx, int gy)
{
    constexpr int MI = (BN == 128) ? 4 : 2;     // 16-row frags per wave
    constexpr int NLOAD = 2 + ((BN == 128) ? 2 : 1);
    __shared__ u16 As[3][128 * 32];
    __shared__ u16 Bs[3][BN * 32];
    const int tid = threadIdx.x;
    const int wid = tid >> 6, lane = tid & 63;
    const int bid = SWZ ? xcd_swz(blockIdx.x, gridDim.x) : (int)blockIdx.x;
    const int col = bid % gx;
    const int rem = bid / gx;
    const int row = rem % gy;
    const int z = rem / gy;
    const int row0 = row * 128, col0 = col * BN;
    const size_t koff = (size_t)z * Ksub;
    const int srA = wid * 32 + (lane >> 2);
    const int sc = (lane & 3) * 8;
    const u16* ag = A + (size_t)(row0 + srA) * lda + koff + sc;
    const int srB = (BN == 128) ? (wid * 32 + (lane >> 2)) : (wid * 16 + (lane >> 2));
    const u16* bg = Bt + (size_t)(col0 + srB) * ldb + koff + sc;
    const int nt = Ksub >> 5;

    auto STAGE = [&](int buf, int t) {
        const u16* a = ag + t * 32;
        const u16* b = bg + t * 32;
        gl2lds(a, &As[buf][wid * 1024]);
        gl2lds(a + (size_t)16 * lda, &As[buf][wid * 1024 + 512]);
        if constexpr (BN == 128) {
            gl2lds(b, &Bs[buf][wid * 1024]);
            gl2lds(b + (size_t)16 * ldb, &Bs[buf][wid * 1024 + 512]);
        } else {
            gl2lds(b, &Bs[buf][wid * 512]);
        }
    };

    f32x4 acc[MI][4];
#pragma unroll
    for (int i = 0; i < MI; ++i)
#pragma unroll
        for (int j = 0; j < 4; ++j) acc[i][j] = (f32x4){0.f, 0.f, 0.f, 0.f};

    const int fr = lane & 15, kb8 = (lane >> 4) * 8;
    const int wrbase = (BN == 128) ? (wid >> 1) * 64 : wid * 32;
    const int wcbase = (BN == 128) ? (wid & 1) * 64 : 0;
    const int paoff = (wrbase + fr) * 32 + kb8;
    const int pboff = (wcbase + fr) * 32 + kb8;

    STAGE(0, 0);
    if (nt > 1) STAGE(1, 1);
    for (int t = 0; t < nt; ++t) {
        if (t + 1 < nt) waitv<NLOAD>(); else waitv<0>();
        __builtin_amdgcn_s_barrier();
        asm volatile("" ::: "memory");
        const int buf = t % 3;
#pragma unroll
        for (int mi = 0; mi < MI; ++mi) {
            bf16x8 af = *(const bf16x8*)&As[buf][paoff + mi * 512];
#pragma unroll
            for (int ni = 0; ni < 4; ++ni) {
                bf16x8 bfv = *(const bf16x8*)&Bs[buf][pboff + ni * 512];
                acc[mi][ni] = __builtin_amdgcn_mfma_f32_16x16x32_bf16(af, bfv, acc[mi][ni], 0, 0, 0);
            }
        }
        if (t + 2 < nt) STAGE((t + 2) % 3, t + 2);
    }

    void* Cp = (z == 0) ? C0 : C1;
    const int fq4 = (lane >> 4) * 4;
#pragma unroll
    for (int mi = 0; mi < MI; ++mi) {
#pragma unroll
        for (int j = 0; j < 4; ++j) {
            const int rw = row0 + wrbase + mi * 16 + fq4 + j;
#pragma unroll
            for (int ni = 0; ni < 4; ++ni) {
                const int cl = col0 + wcbase + ni * 16 + fr;
                float v = acc[mi][ni][j];
                if (bias) v += bscale * bias[cl];
                if (ACT == 1) v = fmaxf(v, 0.f);
                else if (ACT == 2) v = 0.5f * v * (1.f + erff(v * 0.70710678118654752f));
                const size_t off = (size_t)rw * ldc + cl;
                if (OBF16) {
                    ((u16*)Cp)[off] = f2bf(v);
                } else {
                    if (resid) v += RESB ? bf2f(((const u16*)resid)[off])
                                         : ((const float*)resid)[off];
                    ((float*)Cp)[off] = v;
                }
            }
        }
    }
}

// ------------------------------------------- split-K reduce: relu + bf16 out
template<int NP>
__global__ __launch_bounds__(256)
void red_relu_kernel(const float* __restrict__ p0, const float* __restrict__ p1,
                     const float* __restrict__ p2, const float* __restrict__ p3,
                     u16* __restrict__ out)
{
    const int i = (blockIdx.x * 256 + threadIdx.x) * 4;
    float4 a = *(const float4*)(p0 + i);
    float4 b = *(const float4*)(p1 + i);
    a.x += b.x; a.y += b.y; a.z += b.z; a.w += b.w;
    if (NP == 4) {
        float4 c = *(const float4*)(p2 + i);
        float4 d = *(const float4*)(p3 + i);
        a.x += c.x + d.x; a.y += c.y + d.y; a.z += c.z + d.z; a.w += c.w + d.w;
    }
    u16x4 o = {f2bf(fmaxf(a.x, 0.f)), f2bf(fmaxf(a.y, 0.f)),
               f2bf(fmaxf(a.z, 0.f)), f2bf(fmaxf(a.w, 0.f))};
    *(u16x4*)(out + i) = o;
}

// -------- combine: hmid(bf16) = hidden + sum_slot AO_z @ Wo + 4*bo  (K=256)
__global__ __launch_bounds__(256)
void combine_mfma_kernel(const u16* __restrict__ AO, const u16* __restrict__ WoT4,
                         const float* __restrict__ hidden, const float* __restrict__ bo,
                         u16* __restrict__ hmid)
{
    __shared__ u16 As[3][128 * 32];
    __shared__ u16 Bs[3][128 * 32];
    const int tid = threadIdx.x;
    const int wid = tid >> 6, lane = tid & 63;
    const int bid = xcd_swz(blockIdx.x, gridDim.x);   // nwg = 352
    const int row0 = (bid >> 3) * 128, col0 = (bid & 7) * 128;
    const int srA = wid * 32 + (lane >> 2);
    const int sc = (lane & 3) * 8;
    const int arow0 = row0 + srA, arow1 = arow0 + 16;
    const int ab0 = arow0 / TT, at0 = arow0 - ab0 * TT;
    const int ab1 = arow1 / TT, at1 = arow1 - ab1 * TT;
    const u16* abase0 = AO + ((size_t)(ab0 * 4) * TT + at0) * 64 + sc;
    const u16* abase1 = AO + ((size_t)(ab1 * 4) * TT + at1) * 64 + sc;
    const u16* bg = WoT4 + (size_t)(col0 + srA) * 256 + sc;
    const int nt = 8;   // K=256, BK=32

    auto STAGE = [&](int buf, int t) {
        const int k0 = t * 32;
        const size_t delta = (size_t)(k0 >> 6) * (TT * 64) + (k0 & 63);
        gl2lds(abase0 + delta, &As[buf][wid * 1024]);
        gl2lds(abase1 + delta, &As[buf][wid * 1024 + 512]);
        gl2lds(bg + k0, &Bs[buf][wid * 1024]);
        gl2lds(bg + k0 + (size_t)16 * 256, &Bs[buf][wid * 1024 + 512]);
    };

    f32x4 acc[4][4];
#pragma unroll
    for (int i = 0; i < 4; ++i)
#pragma unroll
        for (int j = 0; j < 4; ++j) acc[i][j] = (f32x4){0.f, 0.f, 0.f, 0.f};
    const int fr = lane & 15, kb8 = (lane >> 4) * 8;
    const int wrbase = (wid >> 1) * 64, wcbase = (wid & 1) * 64;
    const int paoff = (wrbase + fr) * 32 + kb8;
    const int pboff = (wcbase + fr) * 32 + kb8;

    STAGE(0, 0);
    STAGE(1, 1);
    for (int t = 0; t < nt; ++t) {
        if (t + 1 < nt) waitv<4>(); else waitv<0>();
        __builtin_amdgcn_s_barrier();
        asm volatile("" ::: "memory");
        const int buf = t % 3;
#pragma unroll
        for (int mi = 0; mi < 4; ++mi) {
            bf16x8 af = *(const bf16x8*)&As[buf][paoff + mi * 512];
#pragma unroll
            for (int ni = 0; ni < 4; ++ni) {
                bf16x8 bfv = *(const bf16x8*)&Bs[buf][pboff + ni * 512];
                acc[mi][ni] = __builtin_amdgcn_mfma_f32_16x16x32_bf16(af, bfv, acc[mi][ni], 0, 0, 0);
            }
        }
        if (t + 2 < nt) STAGE((t + 2) % 3, t + 2);
    }

    const int fq4 = (lane >> 4) * 4;
#pragma unroll
    for (int mi = 0; mi < 4; ++mi)
#pragma unroll
        for (int j = 0; j < 4; ++j) {
            const int rw = row0 + wrbase + mi * 16 + fq4 + j;
#pragma unroll
            for (int ni = 0; ni < 4; ++ni) {
                const int cl = col0 + wcbase + ni * 16 + fr;
                const size_t off = (size_t)rw * DD + cl;
                float v = acc[mi][ni][j] + 4.f * bo[cl] + hidden[off];
                hmid[off] = f2bf(v);
            }
        }
}

// ---------------- fused QKV projection: one block computes Q,K and V^T tiles
__global__ __launch_bounds__(256)
void qkv3_mfma_kernel(const u16* __restrict__ hb, const u16* __restrict__ WqkvT,
                      const float* __restrict__ bq, const float* __restrict__ bk,
                      const float* __restrict__ bv, const int* __restrict__ slot_rule,
                      const float* __restrict__ gatep,
                      u16* __restrict__ Qb, u16* __restrict__ Kb, u16* __restrict__ VT)
{
    const int bid = xcd_swz(blockIdx.x, gridDim.x);
    const int slot = bid & 3;
    const int mt = (bid >> 2) % 11;
    const int b = (bid >> 2) / 11;
    const int z = b * 4 + slot;
    const int r = slot_rule[z];
    const float gv = gatep[b * 3 + ((mt < 2) ? 0 : (mt < 3) ? 1 : 2)];
    __shared__ u16 As[3][64 * 32];
    __shared__ u16 Bs[3][3][64 * 32];
    const int tid = threadIdx.x;
    const int w = tid >> 6, lane = tid & 63;
    const u16* ag = hb + ((size_t)b * TT + mt * 64 + (tid >> 2)) * DD + (tid & 3) * 8;
    const u16* bg0 = WqkvT + (size_t)0 * DD * DD + (size_t)(r * 64 + (tid >> 2)) * DD + (tid & 3) * 8;
    const u16* bg1 = WqkvT + (size_t)1 * DD * DD + (size_t)(r * 64 + (tid >> 2)) * DD + (tid & 3) * 8;
    const u16* bg2 = WqkvT + (size_t)2 * DD * DD + (size_t)(r * 64 + (tid >> 2)) * DD + (tid & 3) * 8;
    auto STAGE = [&](int buf, int t) {
        gl2lds(ag  + t * 32, &As[buf][w * 512]);
        gl2lds(bg0 + t * 32, &Bs[buf][0][w * 512]);
        gl2lds(bg1 + t * 32, &Bs[buf][1][w * 512]);
        gl2lds(bg2 + t * 32, &Bs[buf][2][w * 512]);
    };
    f32x4 accq[4], acck[4], accv[4];
#pragma unroll
    for (int i = 0; i < 4; ++i) {
        accq[i] = (f32x4){0.f, 0.f, 0.f, 0.f};
        acck[i] = (f32x4){0.f, 0.f, 0.f, 0.f};
        accv[i] = (f32x4){0.f, 0.f, 0.f, 0.f};
    }
    const int fr = lane & 15, kb8 = (lane >> 4) * 8;
    const int paoff = (w * 16 + fr) * 32 + kb8;
    const int nt = 32;
    STAGE(0, 0);
    STAGE(1, 1);
    for (int t = 0; t < nt; ++t) {
        if (t + 1 < nt) waitv<4>(); else waitv<0>();
        __builtin_amdgcn_s_barrier();
        asm volatile("" ::: "memory");
        const int buf = t % 3;
        bf16x8 af = *(const bf16x8*)&As[buf][paoff];
#pragma unroll
        for (int ni = 0; ni < 4; ++ni) {
            const int boff = (ni * 16 + fr) * 32 + kb8;
            bf16x8 bq8 = *(const bf16x8*)&Bs[buf][0][boff];
            bf16x8 bk8 = *(const bf16x8*)&Bs[buf][1][boff];
            bf16x8 bv8 = *(const bf16x8*)&Bs[buf][2][boff];
            accq[ni] = __builtin_amdgcn_mfma_f32_16x16x32_bf16(af, bq8, accq[ni], 0, 0, 0);
            acck[ni] = __builtin_amdgcn_mfma_f32_16x16x32_bf16(af, bk8, acck[ni], 0, 0, 0);
            accv[ni] = __builtin_amdgcn_mfma_f32_16x16x32_bf16(bv8, af, accv[ni], 0, 0, 0);
        }
        if (t + 2 < nt) STAGE((t + 2) % 3, t + 2);
    }
    const size_t bs = (size_t)z * TT;
    const int fq4 = (lane >> 4) * 4;
#pragma unroll
    for (int ni = 0; ni < 4; ++ni)
#pragma unroll
        for (int j = 0; j < 4; ++j) {
            const int row = mt * 64 + w * 16 + fq4 + j;
            const int col = ni * 16 + fr;
            Qb[(bs + row) * 64 + col] = f2bf((gv * accq[ni][j] + bq[r * 64 + col]) * 0.125f);
            Kb[(bs + row) * 64 + col] = f2bf(gv * acck[ni][j] + bk[r * 64 + col]);
            const int d = ni * 16 + fq4 + j;
            const int tt2 = mt * 64 + w * 16 + fr;
            VT[((size_t)z * 64 + d) * TT + tt2] = f2bf(gv * accv[ni][j] + bv[r * 64 + d]);
        }
}

// ----------------------------------------- MFMA bf16 flash attention / slot
__global__ __launch_bounds__(256)
void attn_mfma_kernel(const u16* __restrict__ Qb, const u16* __restrict__ Kb,
                      const u16* __restrict__ VT, const float* __restrict__ amask,
                      u16* __restrict__ AO)
{
    const int bid = xcd_swz(blockIdx.x, gridDim.x);
    const int slot = bid & 3;
    const int qt = (bid >> 2) % 11;
    const int b = (bid >> 2) / 11;
    const int z = b * 4 + slot;
    const size_t bs = (size_t)z * TT;
    const int tid = threadIdx.x;
    const int w = tid >> 6, lane = tid & 63;
    const int fr = lane & 15, g = lane >> 4;
    const int q0 = qt * 64 + w * 16;

    __shared__ u16 Ks[64 * 72];    // [key][d], stride 72
    __shared__ u16 VTs[64 * 72];   // [d][key]
    __shared__ u16 Ps[4][16 * 72]; // per-wave P tile [q][key]

    bf16x8 qa[2];
    qa[0] = *(const bf16x8*)(Qb + (bs + q0 + fr) * 64 + g * 8);
    qa[1] = *(const bf16x8*)(Qb + (bs + q0 + fr) * 64 + 32 + g * 8);

    float m_run[4], l_run[4];
    f32x4 oacc[4];
#pragma unroll
    for (int j = 0; j < 4; ++j) { m_run[j] = -1e30f; l_run[j] = 0.f; }
#pragma unroll
    for (int ni = 0; ni < 4; ++ni) oacc[ni] = (f32x4){0.f, 0.f, 0.f, 0.f};

    const float* mrow = amask + ((size_t)b * TT + q0 + g * 4) * TT;

    for (int kc = 0; kc < 11; ++kc) {
        const int kv0 = kc * 64;
        __syncthreads();
#pragma unroll
        for (int it = 0; it < 2; ++it) {
            const int idx = tid + it * 256;
            const int row = idx >> 3, ch = (idx & 7) * 8;
            *(u16x8*)&Ks[row * 72 + ch]  = *(const u16x8*)(Kb + (bs + kv0 + row) * 64 + ch);
            *(u16x8*)&VTs[row * 72 + ch] = *(const u16x8*)(VT + ((size_t)z * 64 + row) * TT + kv0 + ch);
        }
        __syncthreads();
        f32x4 sacc[4];
#pragma unroll
        for (int ni = 0; ni < 4; ++ni) sacc[ni] = (f32x4){0.f, 0.f, 0.f, 0.f};
#pragma unroll
        for (int c = 0; c < 2; ++c)
#pragma unroll
            for (int ni = 0; ni < 4; ++ni) {
                bf16x8 bf = *(const bf16x8*)&Ks[(ni * 16 + fr) * 72 + c * 32 + g * 8];
                sacc[ni] = __builtin_amdgcn_mfma_f32_16x16x32_bf16(qa[c], bf, sacc[ni], 0, 0, 0);
            }
        float mloc[4] = {-1e30f, -1e30f, -1e30f, -1e30f};
#pragma unroll
        for (int ni = 0; ni < 4; ++ni)
#pragma unroll
            for (int j = 0; j < 4; ++j) {
                float s = sacc[ni][j] + mrow[(size_t)j * TT + kv0 + ni * 16 + fr];
                sacc[ni][j] = s;
                mloc[j] = fmaxf(mloc[j], s);
            }
#pragma unroll
        for (int o = 1; o < 16; o <<= 1)
#pragma unroll
            for (int j = 0; j < 4; ++j) mloc[j] = fmaxf(mloc[j], __shfl_xor(mloc[j], o));
        float fac[4], lsum[4];
#pragma unroll
        for (int j = 0; j < 4; ++j) {
            const float mn = fmaxf(m_run[j], mloc[j]);
            fac[j] = __expf(m_run[j] - mn);
            m_run[j] = mn;
            lsum[j] = 0.f;
        }
#pragma unroll
        for (int ni = 0; ni < 4; ++ni)
#pragma unroll
            for (int j = 0; j < 4; ++j) {
                const float p = __expf(sacc[ni][j] - m_run[j]);
                lsum[j] += p;
                Ps[w][(g * 4 + j) * 72 + ni * 16 + fr] = f2bf(p);
            }
#pragma unroll
        for (int o = 1; o < 16; o <<= 1)
#pragma unroll
            for (int j = 0; j < 4; ++j) lsum[j] += __shfl_xor(lsum[j], o);
#pragma unroll
        for (int j = 0; j < 4; ++j) l_run[j] = l_run[j] * fac[j] + lsum[j];
#pragma unroll
        for (int ni = 0; ni < 4; ++ni)
#pragma unroll
            for (int j = 0; j < 4; ++j) oacc[ni][j] *= fac[j];
#pragma unroll
        for (int c = 0; c < 2; ++c) {
            bf16x8 paf = *(const bf16x8*)&Ps[w][fr * 72 + c * 32 + g * 8];
#pragma unroll
            for (int ni = 0; ni < 4; ++ni) {
                bf16x8 vf = *(const bf16x8*)&VTs[(ni * 16 + fr) * 72 + c * 32 + g * 8];
                oacc[ni] = __builtin_amdgcn_mfma_f32_16x16x32_bf16(paf, vf, oacc[ni], 0, 0, 0);
            }
        }
    }
#pragma unroll
    for (int j = 0; j < 4; ++j) {
        const float inv = 1.f / l_run[j];
        const int t = q0 + g * 4 + j;
#pragma unroll
        for (int ni = 0; ni < 4; ++ni)
            AO[(bs + t) * 64 + ni * 16 + fr] = f2bf(oacc[ni][j] * inv);
    }
}

// ---------------------------------------------------------------- launcher
extern "C" void kernel_launch(void* const* d_in, const int* in_sizes, int n_in,
                              void* d_out, int out_size, void* d_ws, size_t ws_size,
                              hipStream_t stream)
{
    const float* hidden = (const float*)d_in[0];
    const float* amask  = (const float*)d_in[1];
    const float* rules  = (const float*)d_in[2];
    const float* W_ent  = (const float*)d_in[3];
    const float* b_ent  = (const float*)d_in[4];
    const float* Wq_er  = (const float*)d_in[5];
    const float* Wk_er  = (const float*)d_in[6];
    const float* Wq_es  = (const float*)d_in[7];
    const float* Wk_es  = (const float*)d_in[8];
    const float* Wq     = (const float*)d_in[9];
    const float* bq     = (const float*)d_in[10];
    const float* Wk     = (const float*)d_in[11];
    const float* bk     = (const float*)d_in[12];
    const float* Wv     = (const float*)d_in[13];
    const float* bv     = (const float*)d_in[14];
    const float* Wo     = (const float*)d_in[15];
    const float* bo     = (const float*)d_in[16];
    const float* ln1_g  = (const float*)d_in[17];
    const float* ln1_b  = (const float*)d_in[18];
    const float* ln2_g  = (const float*)d_in[19];
    const float* ln2_b  = (const float*)d_in[20];
    const float* fc1_w1 = (const float*)d_in[21];
    const float* fc1_w2 = (const float*)d_in[22];
    const float* fc2_w1 = (const float*)d_in[23];
    const float* fc2_w2 = (const float*)d_in[24];

    char* ws = (char*)d_ws;
    // -------- workspace map (bytes); max end 92,274,688 <= proven 92,278,016
    float* h      = (float*)(ws + 0);              // 23,068,672 [ln1..pool_partial]
    u16*   x1     = (u16*)(ws + 0);                //  5,767,168 [G1..G2]
    float* g3p0   = (float*)(ws + 0);              // 11,534,336 [G3..G3red] (over dead x1)
    u16*   fc1w2T = (u16*)(ws + 11534336);         //  4,194,304 [transpose..G2] (in dead h)
    u16*   x3b    = (u16*)(ws + 11534336);         //  5,767,168 [G3red..G4] (over dead fc1w2T/fc2w1T)
    u16*   fc2w1T = (u16*)(ws + 15728640);         //  4,194,304 [transpose..G3] (in dead h)
    u16*   fc2w2T = (u16*)(ws + 19922944);         //  1,048,576 [transpose..G4] (in dead h)
    u16*   fc1w1T = (u16*)(ws + 20971520);         //  1,048,576 [transpose..G1] (in dead h)
    u16*   WoT4   = (u16*)(ws + 22020096);         //    524,288 [transpose..combine] (in dead h)
    u16*   hmid   = (u16*)(ws + 23068672);         // 11,534,336 bf16 [combine..G4]
    float* g3p1   = (float*)(ws + 34603008);       // 11,534,336 [G3..G3red]
    u16*   hb     = (u16*)(ws + 46137344);         // 11,534,336 bf16 LN1 out [ln1..qkv]
    u16*   xln2   = (u16*)(ws + 46137344);         //   (reuse)  [ln2..G1]
    u16*   x2     = (u16*)(ws + 46137344);         // 46,137,344 full [G2..G3]
    u16*   Qb     = (u16*)(ws + 57671680);         //  2,883,584 [qkv..attn]
    u16*   Kb     = (u16*)(ws + 60555264);         //  2,883,584
    u16*   VT     = (u16*)(ws + 66322432);         //  2,883,584
    u16*   AO     = (u16*)(ws + 69206016);         //  2,883,584 [attn..combine]
    float* part   = (float*)(ws + 69206016);       //    360,448 (dead before AO)
    float* ent    = (float*)(ws + 80740352);       //      3,072 [pool_finish..select]
    float* gate   = (float*)(ws + 80743424);       //        128 [select..qkv3]
    int*   srule  = (int*)(ws + 80743552);         //        128 [select..qkv3]
    u16*   WqkvT  = (u16*)(ws + 80743680);         //  6,291,456 [transpose..qkv3]
    float* out    = (float*)d_out;

    // --- LN1 (dual fp32+bf16 out) + selection path
    ln1_dual_kernel<<<BT, 256, 0, stream>>>(hidden, ln1_g, ln1_b, h, hb);
    pool_partial_kernel<<<dim3(11, 8), 256, 0, stream>>>(h, part);
    pool_finish_kernel<<<24, 256, 0, stream>>>(part, W_ent, b_ent, ent);
    select_kernel<<<1, 256, 0, stream>>>(ent, rules, Wq_er, Wk_er, Wq_es, Wk_es, srule, gate);

    // --- all weight transposes in one launch (targets live in dead h)
    transpose_all_kernel<<<8256, 256, 0, stream>>>(Wq, Wk, Wv, Wo, fc1_w1, fc2_w2,
                                                   fc1_w2, fc2_w1,
                                                   WqkvT, WoT4, fc1w1T, fc2w2T,
                                                   fc1w2T, fc2w1T);

    // --- fused QKV (MFMA; gate applied in epilogue; writes Q, K, V^T)
    qkv3_mfma_kernel<<<352, 256, 0, stream>>>(hb, WqkvT, bq, bk, bv, srule, gate,
                                              Qb, Kb, VT);

    // --- attention (MFMA); XCD-swizzled so each XCD owns one batch b
    attn_mfma_kernel<<<352, 256, 0, stream>>>(Qb, Kb, VT, amask, AO);

    // --- combine: hmid(bf16) = hidden + sum_slot AO @ Wo + 4*bo (K=256 GEMM)
    combine_mfma_kernel<<<352, 256, 0, stream>>>(AO, WoT4, hidden, bo, hmid);

    // --- LN2 (bf16 in -> bf16 out)
    ln_kernel<1, 1><<<BT, 256, 0, stream>>>(hmid, ln2_g, ln2_b, xln2);

    // --- G1: x1 = relu(xln2 @ fc1w1T^T)  (fused relu->bf16), swizzled
    gemm2<64, 1, 1, 0, 1><<<352, 256, 0, stream>>>(
        xln2, 1024, fc1w1T, 1024, x1, nullptr, 512, BT, 1024,
        nullptr, nullptr, 0.f, 8, 44);

    // --- G2: x2 = gelu(x1 @ fc1w2T^T), full M; natural order pins B cols/XCD
    gemm2<128, 2, 1, 0, 0><<<1408, 256, 0, stream>>>(
        x1, 512, fc1w2T, 512, x2, nullptr, 4096, BT, 512,
        nullptr, nullptr, 0.f, 32, 44);

    // --- G3: split-K 2 fp32 partials, full M, swizzled
    gemm2<64, 0, 0, 0, 1><<<704, 256, 0, stream>>>(
        x2, 4096, fc2w1T, 4096, g3p0, g3p1, 512, BT, 2048,
        nullptr, nullptr, 0.f, 8, 44);
    red_relu_kernel<2><<<2816, 256, 0, stream>>>(g3p0, g3p1, nullptr, nullptr, x3b);

    // --- G4: out = hmid(bf16) + x3b @ fc2w2T^T, swizzled
    gemm2<64, 0, 0, 1, 1><<<704, 256, 0, stream>>>(
        x3b, 512, fc2w2T, 512, out, nullptr, 1024, BT, 512,
        hmid, nullptr, 0.f, 16, 44);
}